// Round 4
// baseline (814.095 us; speedup 1.0000x reference)
//
#include <hip/hip_runtime.h>
#include <math.h>

// SDNConv: N nodes, K=8 factors, DK=16. ROW = 128 floats/node.
// R10: pull gather reverted to exact R7 body (R9's int4/8-deep hurt:
//      occ 54->44%). Build residual attacked: fill_bucket WN=1024
//      (4 wg/CU); build_csr split into 2 half-blocks per bucket, each
//      owning writers [hf*WN/2,..) and PRIVATE slot range
//      [hf*PAD/2, hf*PAD/2+PAD/2) with counts at cnt[seg*2+hf].
//      Pull hh-lanes read their own half range (replaces mid-split).
// R7: two-phase bucketed CSR build, single-writer L2-resident regions.
//   Segment layout node-major: seg = 4*dst + l.
//   l=0: Ep dst=a nb=b (W rows 0-15),  l=1: Ep dst=b nb=a (rows 16-31),
//   self = rows 32-47,
//   l=2: En dst=a nb=b (rows 48-63),  l=3: En dst=b nb=a (rows 64-79).
// Overflow (cell or slot) -> ovf list -> ovf_kernel pre-accumulates into
// d_out; pull adds it before tanh. Legacy single-pass path kept as
// fallback for tiny workspaces / large N.

#define ROW 128
#define ROW4 32
#define BC   256      // nodes per bucket
#define BSH  8        // log2(BC)

__device__ __forceinline__ void push_entry(
    int* __restrict__ cnt, int* __restrict__ ovfCnt, int* __restrict__ ovf,
    int* __restrict__ idxbuf, int seg, int src, int PAD, int ovfCap)
{
    int slot = atomicAdd(&cnt[seg], 1);
    if (slot < PAD) {
        idxbuf[(size_t)seg * PAD + slot] = src;
    } else {
        int oi = atomicAdd(ovfCnt, 1);
        if (oi < ovfCap) { ovf[2*oi] = seg; ovf[2*oi+1] = src; }
    }
}

// ---------------- fallback single-pass fill (legacy path) -------------
__global__ __launch_bounds__(256) void fill_kernel(
    const int4* __restrict__ Ep2, const int4* __restrict__ En2,
    const int* __restrict__ Ep, const int* __restrict__ En,
    int* __restrict__ cnt, int* __restrict__ ovfCnt, int* __restrict__ ovf,
    int* __restrict__ idxbuf, int Epairs, int Etail, int N, int PAD, int ovfCap)
{
    int i = blockIdx.x * 256 + threadIdx.x;
    int stride = gridDim.x * 256;
    for (int e = i; e < Epairs; e += stride) {
        int4 p = Ep2[e];
        push_entry(cnt, ovfCnt, ovf, idxbuf, 4*p.x + 0, p.y, PAD, ovfCap);
        push_entry(cnt, ovfCnt, ovf, idxbuf, 4*p.y + 1, p.x, PAD, ovfCap);
        push_entry(cnt, ovfCnt, ovf, idxbuf, 4*p.z + 0, p.w, PAD, ovfCap);
        push_entry(cnt, ovfCnt, ovf, idxbuf, 4*p.w + 1, p.z, PAD, ovfCap);
        int4 q = En2[e];
        push_entry(cnt, ovfCnt, ovf, idxbuf, 4*q.x + 2, q.y, PAD, ovfCap);
        push_entry(cnt, ovfCnt, ovf, idxbuf, 4*q.y + 3, q.x, PAD, ovfCap);
        push_entry(cnt, ovfCnt, ovf, idxbuf, 4*q.z + 2, q.w, PAD, ovfCap);
        push_entry(cnt, ovfCnt, ovf, idxbuf, 4*q.w + 3, q.z, PAD, ovfCap);
    }
    if (i == 0 && Etail) {
        int e = 2 * Epairs;
        int a = Ep[2*e], b = Ep[2*e+1];
        push_entry(cnt, ovfCnt, ovf, idxbuf, 4*a + 0, b, PAD, ovfCap);
        push_entry(cnt, ovfCnt, ovf, idxbuf, 4*b + 1, a, PAD, ovfCap);
        int c = En[2*e], d = En[2*e+1];
        push_entry(cnt, ovfCnt, ovf, idxbuf, 4*c + 2, d, PAD, ovfCap);
        push_entry(cnt, ovfCnt, ovf, idxbuf, 4*d + 3, c, PAD, ovfCap);
    }
}

// ---------------- phase 1: bucketed scatter (single-writer cells) -----
// Entry packing: src in bits 0-16 (N < 131072), dst_local in 17-24,
// l in 25-26. Each workgroup w owns cells[w][0..B)[0..CAP) and its own
// LDS counters, so every written cache line has exactly one writer CU.
__global__ __launch_bounds__(256) void fill_bucket(
    const int4* __restrict__ Ep2, const int4* __restrict__ En2,
    const int* __restrict__ Ep, const int* __restrict__ En,
    int* __restrict__ cnt2, int* __restrict__ cells,
    int* __restrict__ ovfCnt, int* __restrict__ ovf,
    int Epairs, int Etail, int B, int CAP, int ovfCap)
{
    __shared__ int lcnt[1024];
    const int w = blockIdx.x;
    int* __restrict__ mycell = cells + (size_t)w * B * CAP;

    for (int i = threadIdx.x; i < 1024; i += 256) lcnt[i] = 0;
    __syncthreads();

    auto pushB = [&](int dst, int l, int src) {
        int bkt  = dst >> BSH;
        int slot = atomicAdd(&lcnt[bkt], 1);
        if (slot < CAP) {
            mycell[(size_t)bkt * CAP + slot] =
                src | ((dst & (BC - 1)) << 17) | (l << 25);
        } else {
            int oi = atomicAdd(ovfCnt, 1);
            if (oi < ovfCap) { ovf[2*oi] = 4*dst + l; ovf[2*oi+1] = src; }
        }
    };

    int stride = gridDim.x * 256;
    for (int e = blockIdx.x * 256 + threadIdx.x; e < Epairs; e += stride) {
        int4 p = Ep2[e];
        pushB(p.x, 0, p.y); pushB(p.y, 1, p.x);
        pushB(p.z, 0, p.w); pushB(p.w, 1, p.z);
        int4 q = En2[e];
        pushB(q.x, 2, q.y); pushB(q.y, 3, q.x);
        pushB(q.z, 2, q.w); pushB(q.w, 3, q.z);
    }
    if (w == 0 && threadIdx.x == 0 && Etail) {
        int e = 2 * Epairs;
        int a = Ep[2*e], b = Ep[2*e+1];
        pushB(a, 0, b); pushB(b, 1, a);
        int c = En[2*e], d = En[2*e+1];
        pushB(c, 2, d); pushB(d, 3, c);
    }
    __syncthreads();
    for (int b = threadIdx.x; b < B; b += 256) {
        int v = lcnt[b];
        cnt2[(size_t)w * B + b] = (v < CAP) ? v : CAP;
    }
}

// ---------------- phase 2: per-bucket counting sort into CSR ----------
// Two half-blocks per bucket (grid = 2*B): half hf owns writers
// [hf*wn/2,(hf+1)*wn/2) and PRIVATE slot range [hf*HP, hf*HP+HP) of each
// segment; counts stored at cnt[seg*2+hf]. Single-writer preserved.
__global__ __launch_bounds__(512) void build_csr(
    const int* __restrict__ cnt2, const int* __restrict__ cells,
    int* __restrict__ cnt, int* __restrict__ idxbuf,
    int* __restrict__ ovfCnt, int* __restrict__ ovf,
    int N, int B, int CAP, int PAD, int wn, int ovfCap)
{
    __shared__ int scnt[4 * BC];
    const int b     = blockIdx.x >> 1;
    const int hf    = blockIdx.x & 1;
    const int HP    = PAD >> 1;
    const int halfW = wn >> 1;
    const int nodeBase = b << BSH;

    for (int i = threadIdx.x; i < 4 * BC; i += 512) scnt[i] = 0;
    __syncthreads();

    auto proc = [&](int p) {
        int src  = p & 0x1FFFF;
        int dl   = (p >> 17) & (BC - 1);
        int l    = (p >> 25) & 3;
        int segl = (dl << 2) | l;
        int slot = atomicAdd(&scnt[segl], 1);
        int seg  = (nodeBase + dl) * 4 + l;
        if (slot < HP) {
            idxbuf[(size_t)seg * PAD + hf * HP + slot] = src;
        } else {
            int oi = atomicAdd(ovfCnt, 1);
            if (oi < ovfCap) { ovf[2*oi] = seg; ovf[2*oi+1] = src; }
        }
    };

    const int wEnd = (hf + 1) * halfW;
    for (int w = hf * halfW + threadIdx.x; w < wEnd; w += 512) {
        int c = cnt2[(size_t)w * B + b];
        const int4* __restrict__ cell4 =
            (const int4*)(cells + ((size_t)w * B + b) * CAP);
        for (int i = 0; i < c; i += 4) {
            int4 v = cell4[i >> 2];
            proc(v.x);
            if (i + 1 < c) proc(v.y);
            if (i + 2 < c) proc(v.z);
            if (i + 3 < c) proc(v.w);
        }
    }
    __syncthreads();
    for (int i = threadIdx.x; i < 4 * BC; i += 512) {
        int node = nodeBase + (i >> 2);
        if (node < N)
            cnt[(((size_t)node * 4 + (i & 3)) << 1) + hf] = scnt[i];
    }
}

// Push overflow entries through their W section into d_out (pre-accumulator).
// Expected count: ~0 (tail probabilities only). Always dispatched.
__global__ __launch_bounds__(256) void ovf_kernel(
    const float* __restrict__ f_in, const float* __restrict__ W,
    const int* __restrict__ ovfCnt, const int* __restrict__ ovf,
    float* __restrict__ out, int N, int ovfCap)
{
    const int t = threadIdx.x & 127;
    const int k = t >> 4;
    const int o = t & 15;
    int nOv = *ovfCnt;
    if (nOv > ovfCap) nOv = ovfCap;
    const int group  = blockIdx.x * 2 + (threadIdx.x >> 7);
    const int stride = gridDim.x * 2;
    for (int i = group; i < nOv; i += stride) {
        int seg = ovf[2*i], src = ovf[2*i+1];
        int l = seg & 3;
        int dst = seg >> 2;
        int s = (l < 2) ? l : l + 1;
        float y = 0.f;
#pragma unroll
        for (int ii = 0; ii < 16; ++ii)
            y += f_in[(size_t)src*ROW + k*16 + ii] * W[k*1280 + (s*16 + ii)*16 + o];
        unsafeAtomicAdd(&out[(size_t)dst*ROW + t], y);
    }
}

// 256 threads per node. Gather roles: oct = tid>>5 -> (list l = oct>>1,
// half hh = oct&1); e4 = tid&31 -> float4 lane of the 512B row.
// SPLIT=1 (bucketed path): hh reads its own private half range
// [hh*HP, hh*HP+cnt[seg*2+hh]); SPLIT=0 (legacy): mid-split of cnt[seg].
// Gather body = exact R7 (scalar idx loads, 4 rows in flight — proven).
// Matmul roles: elem = tid&127 = (k,o), h = tid>>7 halves the W rows;
// partials combined through LDS. 4 barriers/node (R7 phase structure).
__global__ __launch_bounds__(256, 4) void pull_kernel(
    const float4* __restrict__ f_in4,
    const float*  __restrict__ f_in,
    const int*    __restrict__ cnt,
    const int*    __restrict__ idxbuf,
    const float*  __restrict__ W,      // (K, 80, 16)
    const float*  __restrict__ bias,
    const int*    __restrict__ ovfCnt,
    float*        __restrict__ out,    // overflow pre-accum in; final out
    int N, int PAD, int SPLIT)
{
    __shared__ float4 sacc4[2][5][ROW4];   // 5120 B
    __shared__ float  syp[2][ROW];         // 1024 B
    __shared__ float  sa[ROW];             //  512 B

    const int tid  = threadIdx.x;
    const int elem = tid & 127;
    const int h    = tid >> 7;
    const int k    = elem >> 4;
    const int o    = elem & 15;
    const int oct  = tid >> 5;
    const int l    = oct >> 1;
    const int hh   = oct & 1;
    const int e4   = tid & 31;
    const int slot = (l < 2) ? l : l + 1;   // lists -> slots 0,1,3,4
    const int HP   = PAD >> 1;

    float w[5][8];
#pragma unroll
    for (int s = 0; s < 5; ++s)
#pragma unroll
        for (int i = 0; i < 8; ++i)
            w[s][i] = W[k*1280 + (s*16 + h*8 + i)*16 + o];
    const float bb = bias[elem];
    const int haveOvf = *ovfCnt;   // usually 0 -> skip pre-accum reads

    for (int n = blockIdx.x; n < N; n += gridDim.x) {
        float pre = (h == 0 && haveOvf) ? out[(size_t)n*ROW + elem] : 0.f;

        int j, end;
        size_t base;
        if (SPLIT) {
            int c = cnt[(((size_t)4*n + l) << 1) + hh];
            if (c > HP) c = HP;
            base = (size_t)(4*n + l) * PAD + (size_t)hh * HP;
            j = 0; end = c;
        } else {
            int c = cnt[4*n + l];
            if (c > PAD) c = PAD;
            base = (size_t)(4*n + l) * PAD;
            int mid = (c + 1) >> 1;
            j   = hh ? mid : 0;
            end = hh ? c   : mid;
        }

        float4 acc = make_float4(0.f, 0.f, 0.f, 0.f);
        for (; j + 3 < end; j += 4) {       // 4 row-gathers in flight
            int j0 = idxbuf[base + j],     j1 = idxbuf[base + j + 1];
            int j2 = idxbuf[base + j + 2], j3 = idxbuf[base + j + 3];
            float4 r0 = f_in4[(size_t)j0*ROW4 + e4];
            float4 r1 = f_in4[(size_t)j1*ROW4 + e4];
            float4 r2 = f_in4[(size_t)j2*ROW4 + e4];
            float4 r3 = f_in4[(size_t)j3*ROW4 + e4];
            acc.x += r0.x + r1.x + r2.x + r3.x;
            acc.y += r0.y + r1.y + r2.y + r3.y;
            acc.z += r0.z + r1.z + r2.z + r3.z;
            acc.w += r0.w + r1.w + r2.w + r3.w;
        }
        for (; j < end; ++j) {
            float4 r = f_in4[(size_t)idxbuf[base + j]*ROW4 + e4];
            acc.x += r.x; acc.y += r.y; acc.z += r.z; acc.w += r.w;
        }
        sacc4[hh][slot][e4] = acc;
        if (oct == 0) sacc4[0][2][e4] = f_in4[(size_t)n*ROW4 + e4];  // self
        if (oct == 1) sacc4[1][2][e4] = make_float4(0.f, 0.f, 0.f, 0.f);
        __syncthreads();

        float y = 0.f;
#pragma unroll
        for (int s = 0; s < 5; ++s) {
            const float* m0 = (const float*)&sacc4[0][s][0] + k*16 + h*8;
            const float* m1 = (const float*)&sacc4[1][s][0] + k*16 + h*8;
#pragma unroll
            for (int i = 0; i < 8; ++i)
                y += (m0[i] + m1[i]) * w[s][i];
        }
        syp[h][elem] = y;
        __syncthreads();

        float a = 0.f;
        if (h == 0) {
            a = tanhf(syp[0][elem] + syp[1][elem] + bb + pre);
            sa[elem] = a;
        }
        __syncthreads();
        if (h == 0) {
            float ss = 0.f;
#pragma unroll
            for (int k2 = 0; k2 < 8; ++k2) {
                float v = sa[k2*16 + o];
                ss += v * v;
            }
            out[(size_t)n*ROW + elem] = a / fmaxf(sqrtf(ss), 1e-12f);
        }
        __syncthreads();   // protect LDS before next node iteration
    }
}

extern "C" void kernel_launch(void* const* d_in, const int* in_sizes, int n_in,
                              void* d_out, int out_size, void* d_ws, size_t ws_size,
                              hipStream_t stream) {
    const float* f_in = (const float*)d_in[0];
    const int*   Ep   = (const int*)d_in[1];
    const int*   En   = (const int*)d_in[2];
    const float* W    = (const float*)d_in[3];
    const float* b    = (const float*)d_in[4];
    float* out = (float*)d_out;

    const int N = in_sizes[0] / ROW;
    const int E = in_sizes[1] / 2;
    const int Epairs = E / 2;
    const int Etail  = E & 1;
    const int M = 4 * N;                 // CSR segments
    const int B = (N + BC - 1) / BC;     // buckets

    // ---- bucketed path: pick largest (WN, PAD, CAP) that fits --------
    bool newpath = (N <= 131072) && (B <= 1024);
    int PAD = 0, CAP = 0, WN = 0;
    if (newpath) {
        // WN=1024: cell mean = 4E/(1024*B) ~ 16 -> CAP>=32 near-zero ovf.
        const int cfg1k[][2] = {{64,48},{48,40},{48,32},{40,32},{40,24},
                                {32,24},{32,16},{24,16},{16,16}};
        // WN=512: cell mean ~32 -> CAP>=48 preferred.
        const int cfg512[][2] = {{64,48},{56,48},{48,48},{48,40},{40,40},
                                 {40,32},{32,32},{32,24},{24,24},{24,16},
                                 {16,16}};
        const int wnl[2] = {1024, 512};
        for (int wi = 0; wi < 2 && !WN; ++wi) {
            int wn = wnl[wi];
            const int (*cfg)[2] = wi ? cfg512 : cfg1k;
            int ncfg = wi ? 11 : 9;
            for (int i = 0; i < ncfg; ++i) {
                int pad = cfg[i][0], cap = cfg[i][1];
                size_t need = ((size_t)2*M + 64 + (size_t)wn * B
                               + (size_t)M * pad
                               + (size_t)wn * B * cap) * sizeof(int)
                              + 512 * 1024;
                if (need <= ws_size) { PAD = pad; CAP = cap; WN = wn; break; }
            }
        }
        if (!WN) newpath = false;
    }

    if (newpath) {
        // Layout: cnt[2M] | ovfCnt[64] | cnt2[WN*B] | idxbuf[M*PAD]
        //         | cells[WN*B*CAP] | ovf[2*ovfCap]
        int* cnt    = (int*)d_ws;
        int* ovfCnt = cnt + (size_t)2*M;
        int* cnt2   = ovfCnt + 64;
        int* idxbuf = cnt2 + (size_t)WN * B;
        int* cells  = idxbuf + (size_t)M * PAD;
        int* ovf    = cells + (size_t)WN * B * CAP;
        size_t used = ((size_t)2*M + 64 + (size_t)WN * B
                       + (size_t)M * PAD + (size_t)WN * B * CAP) * sizeof(int);
        size_t left = ws_size - used;
        size_t ovfCapSz = left / (2 * sizeof(int));
        int ovfCap = (int)(ovfCapSz > (size_t)(1 << 22) ? (1 << 22) : ovfCapSz);
        if (ovfCap < 1) ovfCap = 1;

        hipMemsetAsync(ovfCnt, 0, 64 * sizeof(int), stream);
        hipMemsetAsync(out, 0, (size_t)out_size * sizeof(float), stream);

        fill_bucket<<<WN, 256, 0, stream>>>((const int4*)Ep, (const int4*)En,
                                            Ep, En, cnt2, cells, ovfCnt, ovf,
                                            Epairs, Etail, B, CAP, ovfCap);
        build_csr<<<2*B, 512, 0, stream>>>(cnt2, cells, cnt, idxbuf,
                                           ovfCnt, ovf, N, B, CAP, PAD, WN,
                                           ovfCap);
        ovf_kernel<<<256, 256, 0, stream>>>(f_in, W, ovfCnt, ovf, out, N, ovfCap);
        pull_kernel<<<8192, 256, 0, stream>>>((const float4*)f_in, f_in, cnt,
                                              idxbuf, W, b, ovfCnt, out, N,
                                              PAD, 1);
        return;
    }

    // ---------------- fallback: legacy single-pass path ----------------
    int PADf = 72;
    size_t fixed;
    do {
        PADf -= 8;
        fixed = ((size_t)M + 64 + (size_t)M * PADf) * sizeof(int);
    } while (PADf > 8 && fixed + 512 * 1024 > ws_size);
    size_t left = (ws_size > fixed) ? (ws_size - fixed) : 8;
    size_t ovfCapSz = left / (2 * sizeof(int));
    int ovfCap = (int)(ovfCapSz > (size_t)(1 << 22) ? (1 << 22) : ovfCapSz);
    if (ovfCap < 1) ovfCap = 1;

    int* cnt    = (int*)d_ws;
    int* ovfCnt = cnt + M;
    int* idxbuf = ovfCnt + 64;
    int* ovf    = idxbuf + (size_t)M * PADf;

    hipMemsetAsync(cnt, 0, ((size_t)M + 64) * sizeof(int), stream);
    hipMemsetAsync(out, 0, (size_t)out_size * sizeof(float), stream);

    fill_kernel<<<2048, 256, 0, stream>>>((const int4*)Ep, (const int4*)En,
                                          Ep, En, cnt, ovfCnt, ovf, idxbuf,
                                          Epairs, Etail, N, PADf, ovfCap);
    ovf_kernel<<<64, 256, 0, stream>>>(f_in, W, ovfCnt, ovf, out, N, ovfCap);
    pull_kernel<<<8192, 256, 0, stream>>>((const float4*)f_in, f_in, cnt,
                                          idxbuf, W, b, ovfCnt, out, N,
                                          PADf, 0);
}

// Round 5
// 779.378 us; speedup vs baseline: 1.0445x; 1.0445x over previous
//
#include <hip/hip_runtime.h>
#include <math.h>

// SDNConv: N nodes, K=8 factors, DK=16. ROW = 128 floats/node.
// R11: repair + instrument.
//  - build/pull contract reverted to proven R7 form: unified cnt[seg],
//    contiguous PAD slots, mid-split gather halves (R10's private halves
//    cost E[max(Bin(c,1/2))] ~ +10% gather imbalance -> +25us).
//  - pull split into TWO half-range dispatches (~250us each): drops the
//    rocprof top-5 visibility floor so fill_bucket/build_csr surface if
//    they are big. Cost <= 10us.
//  - 51-MB memset(out) replaced by 400-KB flag memset + ovf_zero kernel
//    (out fully overwritten by pull; zero-base only needed for overflow
//    rows, which ovf_zero zeros+flags; pull gates pre on nflag[n]).
// R7: two-phase bucketed CSR build, single-writer L2-resident regions.
//   Segment layout node-major: seg = 4*dst + l.
//   l=0: Ep dst=a nb=b (W rows 0-15),  l=1: Ep dst=b nb=a (rows 16-31),
//   self = rows 32-47,
//   l=2: En dst=a nb=b (rows 48-63),  l=3: En dst=b nb=a (rows 64-79).
// Overflow (cell or slot) -> ovf list -> ovf_zero zeros+flags target rows,
// ovf_kernel pre-accumulates into d_out; pull adds it before tanh.
// Legacy single-pass path kept as fallback for tiny ws / large N.

#define ROW 128
#define ROW4 32
#define BC   256      // nodes per bucket
#define BSH  8        // log2(BC)

__device__ __forceinline__ void push_entry(
    int* __restrict__ cnt, int* __restrict__ ovfCnt, int* __restrict__ ovf,
    int* __restrict__ idxbuf, int seg, int src, int PAD, int ovfCap)
{
    int slot = atomicAdd(&cnt[seg], 1);
    if (slot < PAD) {
        idxbuf[(size_t)seg * PAD + slot] = src;
    } else {
        int oi = atomicAdd(ovfCnt, 1);
        if (oi < ovfCap) { ovf[2*oi] = seg; ovf[2*oi+1] = src; }
    }
}

// ---------------- fallback single-pass fill (legacy path) -------------
__global__ __launch_bounds__(256) void fill_kernel(
    const int4* __restrict__ Ep2, const int4* __restrict__ En2,
    const int* __restrict__ Ep, const int* __restrict__ En,
    int* __restrict__ cnt, int* __restrict__ ovfCnt, int* __restrict__ ovf,
    int* __restrict__ idxbuf, int Epairs, int Etail, int N, int PAD, int ovfCap)
{
    int i = blockIdx.x * 256 + threadIdx.x;
    int stride = gridDim.x * 256;
    for (int e = i; e < Epairs; e += stride) {
        int4 p = Ep2[e];
        push_entry(cnt, ovfCnt, ovf, idxbuf, 4*p.x + 0, p.y, PAD, ovfCap);
        push_entry(cnt, ovfCnt, ovf, idxbuf, 4*p.y + 1, p.x, PAD, ovfCap);
        push_entry(cnt, ovfCnt, ovf, idxbuf, 4*p.z + 0, p.w, PAD, ovfCap);
        push_entry(cnt, ovfCnt, ovf, idxbuf, 4*p.w + 1, p.z, PAD, ovfCap);
        int4 q = En2[e];
        push_entry(cnt, ovfCnt, ovf, idxbuf, 4*q.x + 2, q.y, PAD, ovfCap);
        push_entry(cnt, ovfCnt, ovf, idxbuf, 4*q.y + 3, q.x, PAD, ovfCap);
        push_entry(cnt, ovfCnt, ovf, idxbuf, 4*q.z + 2, q.w, PAD, ovfCap);
        push_entry(cnt, ovfCnt, ovf, idxbuf, 4*q.w + 3, q.z, PAD, ovfCap);
    }
    if (i == 0 && Etail) {
        int e = 2 * Epairs;
        int a = Ep[2*e], b = Ep[2*e+1];
        push_entry(cnt, ovfCnt, ovf, idxbuf, 4*a + 0, b, PAD, ovfCap);
        push_entry(cnt, ovfCnt, ovf, idxbuf, 4*b + 1, a, PAD, ovfCap);
        int c = En[2*e], d = En[2*e+1];
        push_entry(cnt, ovfCnt, ovf, idxbuf, 4*c + 2, d, PAD, ovfCap);
        push_entry(cnt, ovfCnt, ovf, idxbuf, 4*d + 3, c, PAD, ovfCap);
    }
}

// ---------------- phase 1: bucketed scatter (single-writer cells) -----
// Entry packing: src in bits 0-16 (N < 131072), dst_local in 17-24,
// l in 25-26. Each workgroup w owns cells[w][0..B)[0..CAP) and its own
// LDS counters, so every written cache line has exactly one writer CU.
__global__ __launch_bounds__(256) void fill_bucket(
    const int4* __restrict__ Ep2, const int4* __restrict__ En2,
    const int* __restrict__ Ep, const int* __restrict__ En,
    int* __restrict__ cnt2, int* __restrict__ cells,
    int* __restrict__ ovfCnt, int* __restrict__ ovf,
    int Epairs, int Etail, int B, int CAP, int ovfCap)
{
    __shared__ int lcnt[1024];
    const int w = blockIdx.x;
    int* __restrict__ mycell = cells + (size_t)w * B * CAP;

    for (int i = threadIdx.x; i < 1024; i += 256) lcnt[i] = 0;
    __syncthreads();

    auto pushB = [&](int dst, int l, int src) {
        int bkt  = dst >> BSH;
        int slot = atomicAdd(&lcnt[bkt], 1);
        if (slot < CAP) {
            mycell[(size_t)bkt * CAP + slot] =
                src | ((dst & (BC - 1)) << 17) | (l << 25);
        } else {
            int oi = atomicAdd(ovfCnt, 1);
            if (oi < ovfCap) { ovf[2*oi] = 4*dst + l; ovf[2*oi+1] = src; }
        }
    };

    int stride = gridDim.x * 256;
    for (int e = blockIdx.x * 256 + threadIdx.x; e < Epairs; e += stride) {
        int4 p = Ep2[e];
        pushB(p.x, 0, p.y); pushB(p.y, 1, p.x);
        pushB(p.z, 0, p.w); pushB(p.w, 1, p.z);
        int4 q = En2[e];
        pushB(q.x, 2, q.y); pushB(q.y, 3, q.x);
        pushB(q.z, 2, q.w); pushB(q.w, 3, q.z);
    }
    if (w == 0 && threadIdx.x == 0 && Etail) {
        int e = 2 * Epairs;
        int a = Ep[2*e], b = Ep[2*e+1];
        pushB(a, 0, b); pushB(b, 1, a);
        int c = En[2*e], d = En[2*e+1];
        pushB(c, 2, d); pushB(d, 3, c);
    }
    __syncthreads();
    for (int b = threadIdx.x; b < B; b += 256) {
        int v = lcnt[b];
        cnt2[(size_t)w * B + b] = (v < CAP) ? v : CAP;
    }
}

// ---------------- phase 2: per-bucket counting sort into CSR ----------
// One block per bucket (grid = B); 512 threads scan all WN writer cells;
// idxbuf window (4*BC*PAD ints) is single-writer and L2-resident.
// cnt[] written directly from LDS (no memset). Unified R7 contract.
__global__ __launch_bounds__(512) void build_csr(
    const int* __restrict__ cnt2, const int* __restrict__ cells,
    int* __restrict__ cnt, int* __restrict__ idxbuf,
    int* __restrict__ ovfCnt, int* __restrict__ ovf,
    int N, int B, int CAP, int PAD, int WN, int ovfCap)
{
    __shared__ int scnt[4 * BC];
    const int b = blockIdx.x;
    const int nodeBase = b << BSH;

    for (int i = threadIdx.x; i < 4 * BC; i += 512) scnt[i] = 0;
    __syncthreads();

    auto proc = [&](int p) {
        int src  = p & 0x1FFFF;
        int dl   = (p >> 17) & (BC - 1);
        int l    = (p >> 25) & 3;
        int segl = (dl << 2) | l;
        int slot = atomicAdd(&scnt[segl], 1);
        if (slot < PAD) {
            idxbuf[(size_t)((nodeBase + dl) * 4 + l) * PAD + slot] = src;
        } else {
            int oi = atomicAdd(ovfCnt, 1);
            if (oi < ovfCap) {
                ovf[2*oi] = (nodeBase + dl) * 4 + l; ovf[2*oi+1] = src;
            }
        }
    };

    for (int w = threadIdx.x; w < WN; w += 512) {
        int c = cnt2[(size_t)w * B + b];
        const int4* __restrict__ cell4 =
            (const int4*)(cells + ((size_t)w * B + b) * CAP);
        for (int i = 0; i < c; i += 4) {
            int4 v = cell4[i >> 2];
            proc(v.x);
            if (i + 1 < c) proc(v.y);
            if (i + 2 < c) proc(v.z);
            if (i + 3 < c) proc(v.w);
        }
    }
    __syncthreads();
    for (int i = threadIdx.x; i < 4 * BC; i += 512) {
        int node = nodeBase + (i >> 2);
        if (node < N) cnt[node * 4 + (i & 3)] = scnt[i];
    }
}

// Zero + flag the rows that will receive overflow pre-accumulation.
// Runs before ovf_kernel; benign write races (all lanes write 0 / 1).
__global__ __launch_bounds__(128) void ovf_zero(
    const int* __restrict__ ovfCnt, const int* __restrict__ ovf,
    float* __restrict__ out, int* __restrict__ nflag, int ovfCap)
{
    const int t = threadIdx.x;      // 0..127
    int nOv = *ovfCnt;
    if (nOv > ovfCap) nOv = ovfCap;
    for (int i = blockIdx.x; i < nOv; i += gridDim.x) {
        int dst = ovf[2*i] >> 2;
        out[(size_t)dst*ROW + t] = 0.f;
        if (t == 0) nflag[dst] = 1;
    }
}

// Push overflow entries through their W section into d_out (pre-accumulator).
// Expected count: ~0 (tail probabilities only). Always dispatched.
__global__ __launch_bounds__(256) void ovf_kernel(
    const float* __restrict__ f_in, const float* __restrict__ W,
    const int* __restrict__ ovfCnt, const int* __restrict__ ovf,
    float* __restrict__ out, int N, int ovfCap)
{
    const int t = threadIdx.x & 127;
    const int k = t >> 4;
    const int o = t & 15;
    int nOv = *ovfCnt;
    if (nOv > ovfCap) nOv = ovfCap;
    const int group  = blockIdx.x * 2 + (threadIdx.x >> 7);
    const int stride = gridDim.x * 2;
    for (int i = group; i < nOv; i += stride) {
        int seg = ovf[2*i], src = ovf[2*i+1];
        int l = seg & 3;
        int dst = seg >> 2;
        int s = (l < 2) ? l : l + 1;
        float y = 0.f;
#pragma unroll
        for (int ii = 0; ii < 16; ++ii)
            y += f_in[(size_t)src*ROW + k*16 + ii] * W[k*1280 + (s*16 + ii)*16 + o];
        unsafeAtomicAdd(&out[(size_t)dst*ROW + t], y);
    }
}

// 256 threads per node. Gather roles: oct = tid>>5 -> (list l = oct>>1,
// half hh = oct&1); e4 = tid&31 -> float4 lane of the 512B row. Mid-split
// of cnt[seg] between hh halves (R7-proven body: scalar idx loads, 4 rows
// in flight). Matmul roles: elem = tid&127 = (k,o), h = tid>>7 halves the
// W rows; partials combined through LDS. 4 barriers/node.
// Dispatched twice over [nStart,nEnd) halves (instrumentation split).
__global__ __launch_bounds__(256, 4) void pull_kernel(
    const float4* __restrict__ f_in4,
    const float*  __restrict__ f_in,
    const int*    __restrict__ cnt,
    const int*    __restrict__ idxbuf,
    const float*  __restrict__ W,      // (K, 80, 16)
    const float*  __restrict__ bias,
    const int*    __restrict__ ovfCnt,
    const int*    __restrict__ nflag,
    float*        __restrict__ out,    // overflow pre-accum in; final out
    int nStart, int nEnd, int PAD)
{
    __shared__ float4 sacc4[2][5][ROW4];   // 5120 B
    __shared__ float  syp[2][ROW];         // 1024 B
    __shared__ float  sa[ROW];             //  512 B

    const int tid  = threadIdx.x;
    const int elem = tid & 127;
    const int h    = tid >> 7;
    const int k    = elem >> 4;
    const int o    = elem & 15;
    const int oct  = tid >> 5;
    const int l    = oct >> 1;
    const int hh   = oct & 1;
    const int e4   = tid & 31;
    const int slot = (l < 2) ? l : l + 1;   // lists -> slots 0,1,3,4

    float w[5][8];
#pragma unroll
    for (int s = 0; s < 5; ++s)
#pragma unroll
        for (int i = 0; i < 8; ++i)
            w[s][i] = W[k*1280 + (s*16 + h*8 + i)*16 + o];
    const float bb = bias[elem];
    const int haveOvf = *ovfCnt;   // usually 0 -> skip pre-accum reads

    for (int n = nStart + blockIdx.x; n < nEnd; n += gridDim.x) {
        float pre = 0.f;
        if (h == 0 && haveOvf)
            pre = nflag[n] ? out[(size_t)n*ROW + elem] : 0.f;

        int c = cnt[4*n + l];
        if (c > PAD) c = PAD;
        const size_t base = (size_t)(4*n + l) * PAD;
        const int mid = (c + 1) >> 1;
        int j         = hh ? mid : 0;
        const int end = hh ? c   : mid;

        float4 acc = make_float4(0.f, 0.f, 0.f, 0.f);
        for (; j + 3 < end; j += 4) {       // 4 row-gathers in flight
            int j0 = idxbuf[base + j],     j1 = idxbuf[base + j + 1];
            int j2 = idxbuf[base + j + 2], j3 = idxbuf[base + j + 3];
            float4 r0 = f_in4[(size_t)j0*ROW4 + e4];
            float4 r1 = f_in4[(size_t)j1*ROW4 + e4];
            float4 r2 = f_in4[(size_t)j2*ROW4 + e4];
            float4 r3 = f_in4[(size_t)j3*ROW4 + e4];
            acc.x += r0.x + r1.x + r2.x + r3.x;
            acc.y += r0.y + r1.y + r2.y + r3.y;
            acc.z += r0.z + r1.z + r2.z + r3.z;
            acc.w += r0.w + r1.w + r2.w + r3.w;
        }
        for (; j < end; ++j) {
            float4 r = f_in4[(size_t)idxbuf[base + j]*ROW4 + e4];
            acc.x += r.x; acc.y += r.y; acc.z += r.z; acc.w += r.w;
        }
        sacc4[hh][slot][e4] = acc;
        if (oct == 0) sacc4[0][2][e4] = f_in4[(size_t)n*ROW4 + e4];  // self
        if (oct == 1) sacc4[1][2][e4] = make_float4(0.f, 0.f, 0.f, 0.f);
        __syncthreads();

        float y = 0.f;
#pragma unroll
        for (int s = 0; s < 5; ++s) {
            const float* m0 = (const float*)&sacc4[0][s][0] + k*16 + h*8;
            const float* m1 = (const float*)&sacc4[1][s][0] + k*16 + h*8;
#pragma unroll
            for (int i = 0; i < 8; ++i)
                y += (m0[i] + m1[i]) * w[s][i];
        }
        syp[h][elem] = y;
        __syncthreads();

        float a = 0.f;
        if (h == 0) {
            a = tanhf(syp[0][elem] + syp[1][elem] + bb + pre);
            sa[elem] = a;
        }
        __syncthreads();
        if (h == 0) {
            float ss = 0.f;
#pragma unroll
            for (int k2 = 0; k2 < 8; ++k2) {
                float v = sa[k2*16 + o];
                ss += v * v;
            }
            out[(size_t)n*ROW + elem] = a / fmaxf(sqrtf(ss), 1e-12f);
        }
        __syncthreads();   // protect LDS before next node iteration
    }
}

extern "C" void kernel_launch(void* const* d_in, const int* in_sizes, int n_in,
                              void* d_out, int out_size, void* d_ws, size_t ws_size,
                              hipStream_t stream) {
    const float* f_in = (const float*)d_in[0];
    const int*   Ep   = (const int*)d_in[1];
    const int*   En   = (const int*)d_in[2];
    const float* W    = (const float*)d_in[3];
    const float* b    = (const float*)d_in[4];
    float* out = (float*)d_out;

    const int N = in_sizes[0] / ROW;
    const int E = in_sizes[1] / 2;
    const int Epairs = E / 2;
    const int Etail  = E & 1;
    const int M = 4 * N;                 // CSR segments
    const int B = (N + BC - 1) / BC;     // buckets
    const int Nh = N >> 1;

    // ---- bucketed path: pick largest (WN, PAD, CAP) that fits --------
    bool newpath = (N <= 131072) && (B <= 1024);
    int PAD = 0, CAP = 0, WN = 0;
    if (newpath) {
        // WN=1024: cell mean ~16 -> CAP>=32 near-zero ovf.
        const int cfg1k[][2]  = {{48,32},{40,32},{32,32},{32,24},{24,24},
                                 {24,16},{16,16}};
        // WN=512: cell mean ~32 -> CAP>=48 preferred.
        const int cfg512[][2] = {{64,48},{48,48},{48,40},{40,40},{40,32},
                                 {32,32},{32,24},{24,24},{16,16}};
        const int wnl[2] = {1024, 512};
        for (int wi = 0; wi < 2 && !WN; ++wi) {
            int wn = wnl[wi];
            const int (*cfg)[2] = wi ? cfg512 : cfg1k;
            int ncfg = wi ? 9 : 7;
            for (int i = 0; i < ncfg; ++i) {
                int pad = cfg[i][0], cap = cfg[i][1];
                size_t need = ((size_t)M + 64 + N + (size_t)wn * B
                               + (size_t)M * pad
                               + (size_t)wn * B * cap) * sizeof(int)
                              + 512 * 1024;
                if (need <= ws_size) { PAD = pad; CAP = cap; WN = wn; break; }
            }
        }
        if (!WN) newpath = false;
    }

    if (newpath) {
        // Layout: cnt[M] | ovfCnt[64] | nflag[N] | cnt2[WN*B]
        //         | idxbuf[M*PAD] | cells[WN*B*CAP] | ovf[2*ovfCap]
        int* cnt    = (int*)d_ws;
        int* ovfCnt = cnt + M;
        int* nflag  = ovfCnt + 64;
        int* cnt2   = nflag + N;
        int* idxbuf = cnt2 + (size_t)WN * B;
        int* cells  = idxbuf + (size_t)M * PAD;
        int* ovf    = cells + (size_t)WN * B * CAP;
        size_t used = ((size_t)M + 64 + N + (size_t)WN * B
                       + (size_t)M * PAD + (size_t)WN * B * CAP) * sizeof(int);
        size_t left = ws_size - used;
        size_t ovfCapSz = left / (2 * sizeof(int));
        int ovfCap = (int)(ovfCapSz > (size_t)(1 << 22) ? (1 << 22) : ovfCapSz);
        if (ovfCap < 1) ovfCap = 1;

        // one small memset covers ovfCnt + nflag (contiguous)
        hipMemsetAsync(ovfCnt, 0, ((size_t)64 + N) * sizeof(int), stream);

        fill_bucket<<<WN, 256, 0, stream>>>((const int4*)Ep, (const int4*)En,
                                            Ep, En, cnt2, cells, ovfCnt, ovf,
                                            Epairs, Etail, B, CAP, ovfCap);
        build_csr<<<B, 512, 0, stream>>>(cnt2, cells, cnt, idxbuf,
                                         ovfCnt, ovf, N, B, CAP, PAD, WN,
                                         ovfCap);
        ovf_zero<<<256, 128, 0, stream>>>(ovfCnt, ovf, out, nflag, ovfCap);
        ovf_kernel<<<256, 256, 0, stream>>>(f_in, W, ovfCnt, ovf, out, N,
                                            ovfCap);
        pull_kernel<<<8192, 256, 0, stream>>>((const float4*)f_in, f_in, cnt,
                                              idxbuf, W, b, ovfCnt, nflag,
                                              out, 0, Nh, PAD);
        pull_kernel<<<8192, 256, 0, stream>>>((const float4*)f_in, f_in, cnt,
                                              idxbuf, W, b, ovfCnt, nflag,
                                              out, Nh, N, PAD);
        return;
    }

    // ---------------- fallback: legacy single-pass path ----------------
    int PADf = 72;
    size_t fixed;
    do {
        PADf -= 8;
        fixed = ((size_t)M + 64 + N + (size_t)M * PADf) * sizeof(int);
    } while (PADf > 8 && fixed + 512 * 1024 > ws_size);
    size_t left = (ws_size > fixed) ? (ws_size - fixed) : 8;
    size_t ovfCapSz = left / (2 * sizeof(int));
    int ovfCap = (int)(ovfCapSz > (size_t)(1 << 22) ? (1 << 22) : ovfCapSz);
    if (ovfCap < 1) ovfCap = 1;

    // Layout: cnt[M] | ovfCnt[64] | nflag[N] | idxbuf[M*PADf] | ovf
    int* cnt    = (int*)d_ws;
    int* ovfCnt = cnt + M;
    int* nflag  = ovfCnt + 64;
    int* idxbuf = nflag + N;
    int* ovf    = idxbuf + (size_t)M * PADf;

    hipMemsetAsync(cnt, 0, ((size_t)M + 64 + N) * sizeof(int), stream);

    fill_kernel<<<2048, 256, 0, stream>>>((const int4*)Ep, (const int4*)En,
                                          Ep, En, cnt, ovfCnt, ovf, idxbuf,
                                          Epairs, Etail, N, PADf, ovfCap);
    ovf_zero<<<256, 128, 0, stream>>>(ovfCnt, ovf, out, nflag, ovfCap);
    ovf_kernel<<<256, 256, 0, stream>>>(f_in, W, ovfCnt, ovf, out, N, ovfCap);
    pull_kernel<<<8192, 256, 0, stream>>>((const float4*)f_in, f_in, cnt,
                                          idxbuf, W, b, ovfCnt, nflag,
                                          out, 0, N, PADf);
}